// Round 7
// baseline (282.917 us; speedup 1.0000x reference)
//
#include <hip/hip_runtime.h>
#include <hip/hip_bf16.h>

#define EMBED 1024
#define HEADS 16
#define HD 64
#define NB 2
#define LSEQ 2048

typedef __bf16 bf16x8 __attribute__((ext_vector_type(8)));
typedef float f32x4 __attribute__((ext_vector_type(4)));

static __device__ __forceinline__ __bf16 f2b(float x) {
    union { __hip_bfloat16 h; __bf16 b; } u;
    u.h = __float2bfloat16(x);
    return u.b;
}
static __device__ __forceinline__ bf16x8 cvt8(float4 a, float4 b) {
    bf16x8 r;
    r[0] = f2b(a.x); r[1] = f2b(a.y); r[2] = f2b(a.z); r[3] = f2b(a.w);
    r[4] = f2b(b.x); r[5] = f2b(b.y); r[6] = f2b(b.z); r[7] = f2b(b.w);
    return r;
}
static __device__ __forceinline__ unsigned short b2u(float x) {
    union { __hip_bfloat16 h; unsigned short u; } c;
    c.h = __float2bfloat16(x);
    return c.u;
}

// async global->LDS, 16B per lane; LDS dest = wave-uniform base + lane*16
#define GLD16(g, l) __builtin_amdgcn_global_load_lds( \
    (const __attribute__((address_space(1))) void*)(g), \
    (__attribute__((address_space(3))) void*)(l), 16, 0, 0)

// ---------------------------------------------------------------------------
// Kernel 1: QKV projection via MFMA, fp32 in, bf16 out. Q is scaled by
// log2(e)/32 so attention can use v_exp_f32 (2^x) directly.
// Q/K: D = W·Xᵀ (C-rows = e, contiguous in [l][e] output -> packed 8B store);
// V: D = X·Wᵀ (C-rows = l, contiguous in Vt[d][l] -> packed 8B store).
// ---------------------------------------------------------------------------
__global__ __launch_bounds__(256) void proj_kernel(
    const float* __restrict__ vals,
    const float* __restrict__ keys,
    const float* __restrict__ quer,
    const float* __restrict__ Wv,
    const float* __restrict__ Wk,
    const float* __restrict__ Wq,
    __hip_bfloat16* __restrict__ Qp,
    __hip_bfloat16* __restrict__ Kp,
    __hip_bfloat16* __restrict__ Vt)
{
    int b      = blockIdx.x;
    int tensor = b % 3;
    int rem    = b / 3;                 // [n(1) | lt(5) | hg(2)]
    int n      = rem >> 7;
    int lt     = (rem >> 2) & 31;
    int hg     = rem & 3;
    int t = threadIdx.x, w = t >> 6, lane = t & 63;
    int m16 = lane & 15, quad = lane >> 4;
    int l0 = lt * 64 + w * 16;

    const float* X = (tensor == 0) ? quer : (tensor == 1 ? keys : vals);
    const float* W = (tensor == 0) ? Wq   : (tensor == 1 ? Wk   : Wv);
    // 1/sqrt(1024) * log2(e): QK^T then lands directly in exp2 domain
    float scale = (tensor == 0) ? (1.44269504088896340736f / 32.0f) : 1.0f;

    bf16x8 wf[4][2];
#pragma unroll
    for (int f = 0; f < 4; ++f)
#pragma unroll
        for (int kk = 0; kk < 2; ++kk) {
            const float* wp = W + (f * 16 + m16) * HD + kk * 32 + quad * 8;
            wf[f][kk] = cvt8(*(const float4*)wp, *(const float4*)(wp + 4));
        }

#pragma unroll
    for (int hh = 0; hh < 4; ++hh) {
        int h = hg * 4 + hh;
        const float* xb = X + ((size_t)n * LSEQ + l0 + m16) * EMBED + h * HD + quad * 8;
        bf16x8 xf[2];
#pragma unroll
        for (int kk = 0; kk < 2; ++kk)
            xf[kk] = cvt8(*(const float4*)(xb + kk * 32), *(const float4*)(xb + kk * 32 + 4));

        size_t nh = (size_t)(n * HEADS + h);
        if (tensor != 2) {
            f32x4 acc[4] = {};
#pragma unroll
            for (int f = 0; f < 4; ++f) {
                acc[f] = __builtin_amdgcn_mfma_f32_16x16x32_bf16(wf[f][0], xf[0], acc[f], 0, 0, 0);
                acc[f] = __builtin_amdgcn_mfma_f32_16x16x32_bf16(wf[f][1], xf[1], acc[f], 0, 0, 0);
            }
            __hip_bfloat16* Yp = (tensor == 0) ? Qp : Kp;
#pragma unroll
            for (int f = 0; f < 4; ++f) {
                union { ushort4 u; unsigned short s[4]; } p;
#pragma unroll
                for (int r = 0; r < 4; ++r) p.s[r] = b2u(acc[f][r] * scale);
                *(ushort4*)&Yp[(nh * LSEQ + l0 + m16) * HD + f * 16 + quad * 4] = p.u;
            }
        } else {
            f32x4 acc[4] = {};
#pragma unroll
            for (int f = 0; f < 4; ++f) {
                acc[f] = __builtin_amdgcn_mfma_f32_16x16x32_bf16(xf[0], wf[f][0], acc[f], 0, 0, 0);
                acc[f] = __builtin_amdgcn_mfma_f32_16x16x32_bf16(xf[1], wf[f][1], acc[f], 0, 0, 0);
            }
#pragma unroll
            for (int f = 0; f < 4; ++f) {
                union { ushort4 u; unsigned short s[4]; } p;
#pragma unroll
                for (int r = 0; r < 4; ++r) p.s[r] = b2u(acc[f][r]);
                *(ushort4*)&Vt[(nh * HD + f * 16 + m16) * LSEQ + l0 + quad * 4] = p.u;
            }
        }
    }
}

// ---------------------------------------------------------------------------
// Kernel 1b: Wo fp32 -> bf16.
// ---------------------------------------------------------------------------
__global__ __launch_bounds__(256) void wcvt_kernel(
    const float* __restrict__ Wo, __hip_bfloat16* __restrict__ Wob)
{
    int base = (blockIdx.x * 256 + threadIdx.x) * 16;
#pragma unroll
    for (int j = 0; j < 16; j += 4) {
        float4 w4 = *(const float4*)(Wo + base + j);
        __hip_bfloat16 o[4] = {
            __float2bfloat16(w4.x), __float2bfloat16(w4.y),
            __float2bfloat16(w4.z), __float2bfloat16(w4.w)};
        *(ushort4*)(Wob + base + j) = *(const ushort4*)o;
    }
}

// ---------------------------------------------------------------------------
// Kernel 2: flash attention v4. 2048 blocks x 4 waves; block = (head, 32 q);
// wave w owns keys [w*512, (w+1)*512) -- exact 4-way split-K (additive
// unnormalized softmax), combined via LDS tree at the end.
// exp2-domain scores (log2e folded into Qp). P packed to bf16 by TRUNCATION
// (v_perm_b32, 1 instr/pair): truncation bias cancels in the normalization.
// P pipelined through double-buffered LDS -- no in-loop barrier.
// ---------------------------------------------------------------------------
#define KCH 16
__global__ __launch_bounds__(256) void attn_kernel(
    const __hip_bfloat16* __restrict__ Qp,
    const __hip_bfloat16* __restrict__ Kp,
    const __hip_bfloat16* __restrict__ Vt,
    __hip_bfloat16* __restrict__ AO)
{
    __shared__ __align__(16) __hip_bfloat16 Pb[2][4][32][40];  // 20480 B
    __shared__ float Ls[4][32];

    int i  = blockIdx.x;              // 2048
    int x  = i & 7;                   // XCD (heuristic): 4 heads pinned per XCD
    int r2 = i >> 3;                  // 0..255
    int nh = x * 4 + (r2 >> 6);       // 0..31
    int qt = r2 & 63;

    int t = threadIdx.x, w = t >> 6, lane = t & 63;
    int m16 = lane & 15, quad = lane >> 4;
    int q0 = qt * 32;
    int kbase = w * 512;

    const __hip_bfloat16* qb = Qp + ((size_t)nh * LSEQ + q0 + m16) * HD + quad * 8;
    bf16x8 qf[2][2];
#pragma unroll
    for (int tq = 0; tq < 2; ++tq)
#pragma unroll
        for (int kk = 0; kk < 2; ++kk)
            qf[tq][kk] = *(const bf16x8*)(qb + tq * 16 * HD + kk * 32);

    // K tile t2 covers keys {2j+t2}: interleaved so exp pairs pack to one b32
    const __hip_bfloat16* kp = Kp + ((size_t)nh * LSEQ + kbase + 2 * m16) * HD + quad * 8;
    const __hip_bfloat16* vp = Vt + ((size_t)nh * HD + m16) * LSEQ + kbase + quad * 8;

    f32x4 of[2][4] = {};
    float ls[2][4] = {};
    bf16x8 kf[2][2], vf[4], pf[2];

    for (int c = 0; c <= KCH; ++c) {
        if (c < KCH) {  // K(c) first: longest latency to its consumer S(c)
            const __hip_bfloat16* kc = kp + (size_t)c * 32 * HD;
            kf[0][0] = *(const bf16x8*)(kc);
            kf[0][1] = *(const bf16x8*)(kc + 32);
            kf[1][0] = *(const bf16x8*)(kc + HD);
            kf[1][1] = *(const bf16x8*)(kc + HD + 32);
        }
        if (c > 0) {    // read P(c-1), PV with V(c-1)
            pf[0] = *(const bf16x8*)&Pb[(c - 1) & 1][w][m16][quad * 8];
            pf[1] = *(const bf16x8*)&Pb[(c - 1) & 1][w][16 + m16][quad * 8];
#pragma unroll
            for (int tq = 0; tq < 2; ++tq)
#pragma unroll
                for (int f = 0; f < 4; ++f)
                    of[tq][f] = __builtin_amdgcn_mfma_f32_16x16x32_bf16(
                        pf[tq], vf[f], of[tq][f], 0, 0, 0);
        }
        if (c < KCH) {
#pragma unroll
            for (int f = 0; f < 4; ++f)   // V(c), used next iteration
                vf[f] = *(const bf16x8*)(vp + (size_t)(f * 16) * LSEQ + c * 32);

            f32x4 s[2][2];
#pragma unroll
            for (int tq = 0; tq < 2; ++tq)
#pragma unroll
                for (int t2 = 0; t2 < 2; ++t2) {
                    f32x4 z = {};
                    z = __builtin_amdgcn_mfma_f32_16x16x32_bf16(qf[tq][0], kf[t2][0], z, 0, 0, 0);
                    z = __builtin_amdgcn_mfma_f32_16x16x32_bf16(qf[tq][1], kf[t2][1], z, 0, 0, 0);
                    s[tq][t2] = z;
                }
#pragma unroll
            for (int tq = 0; tq < 2; ++tq)
#pragma unroll
                for (int r = 0; r < 4; ++r) {
                    float e0 = __builtin_amdgcn_exp2f(s[tq][0][r]);   // key 2*m16
                    float e1 = __builtin_amdgcn_exp2f(s[tq][1][r]);   // key 2*m16+1
                    ls[tq][r] += e0 + e1;
                    unsigned u = __builtin_amdgcn_perm(
                        __float_as_uint(e1), __float_as_uint(e0), 0x07060302);
                    *(unsigned*)&Pb[c & 1][w][tq * 16 + quad * 4 + r][2 * m16] = u;
                }
        }
    }

    // reduce ls over the 16 key-lanes; stash per-wave row sums
#pragma unroll
    for (int tq = 0; tq < 2; ++tq)
#pragma unroll
        for (int r = 0; r < 4; ++r) {
            float v = ls[tq][r];
            v += __shfl_xor(v, 1);
            v += __shfl_xor(v, 2);
            v += __shfl_xor(v, 4);
            v += __shfl_xor(v, 8);
            if (m16 == 0) Ls[w][tq * 16 + quad * 4 + r] = v;
        }

    // ---- 4-way split-K combine (LDS tree, reusing Pb) ----
    __syncthreads();
    float* Cb = (float*)&Pb[0][0][0][0];   // 2 x 2048 floats used
    if (w & 1) {
        float* dst = Cb + (w >> 1) * 2048;
#pragma unroll
        for (int tq = 0; tq < 2; ++tq)
#pragma unroll
            for (int f = 0; f < 4; ++f)
                *(f32x4*)&dst[(tq * 4 + f) * 256 + lane * 4] = of[tq][f];
    }
    __syncthreads();
    if (!(w & 1)) {
        const float* src = Cb + (w >> 1) * 2048;
#pragma unroll
        for (int tq = 0; tq < 2; ++tq)
#pragma unroll
            for (int f = 0; f < 4; ++f)
                of[tq][f] += *(const f32x4*)&src[(tq * 4 + f) * 256 + lane * 4];
    }
    __syncthreads();
    if (w == 2) {
#pragma unroll
        for (int tq = 0; tq < 2; ++tq)
#pragma unroll
            for (int f = 0; f < 4; ++f)
                *(f32x4*)&Cb[(tq * 4 + f) * 256 + lane * 4] = of[tq][f];
    }
    __syncthreads();
    if (w == 0) {
        int n = nh >> 4, h = nh & 15;
#pragma unroll
        for (int tq = 0; tq < 2; ++tq)
#pragma unroll
            for (int f = 0; f < 4; ++f)
                of[tq][f] += *(const f32x4*)&Cb[(tq * 4 + f) * 256 + lane * 4];
#pragma unroll
        for (int tq = 0; tq < 2; ++tq)
#pragma unroll
            for (int r = 0; r < 4; ++r) {
                int row = tq * 16 + quad * 4 + r;
                float l = Ls[0][row] + Ls[1][row] + Ls[2][row] + Ls[3][row];
                float rinv = 1.0f / l;
#pragma unroll
                for (int f = 0; f < 4; ++f)
                    AO[((size_t)n * LSEQ + q0 + row) * EMBED + h * HD + f * 16 + m16] =
                        __float2bfloat16(of[tq][f][r] * rinv);
            }
    }
}

// ---------------------------------------------------------------------------
// Kernel 3: out = AO @ Wobᵀ + bo (fp32 out), m97-style LDS-staged GEMM.
// Tile 128x64, BK=32, global_load_lds width-16 staging, 2-barrier K-loop.
// grid 32 mt x 16 nt = 512 blocks of 256; wave w computes rows w*32..+31.
// ---------------------------------------------------------------------------
__global__ __launch_bounds__(256) void outproj_kernel(
    const __hip_bfloat16* __restrict__ AO,
    const __hip_bfloat16* __restrict__ Wob,
    const float* __restrict__ bo,
    float* __restrict__ out)
{
    __shared__ __align__(16) __hip_bfloat16 As[128 * 32];  // 8 KB
    __shared__ __align__(16) __hip_bfloat16 Bs[64 * 32];   // 4 KB

    int b  = blockIdx.x;
    int mt = b >> 4, nt = b & 15;
    int m0 = mt * 128, n0 = nt * 64;
    int t = threadIdx.x, w = t >> 6, lane = t & 63;
    int m16 = lane & 15, quad = lane >> 4;

    int srow = lane >> 2;            // staging: 16 rows per wave-instr
    int scol = (lane & 3) * 8;       // 4 x 8 bf16 = 64B per row

    const __hip_bfloat16* Ab = AO  + (size_t)m0 * EMBED;
    const __hip_bfloat16* Bb = Wob + (size_t)n0 * EMBED;

    f32x4 acc[2][4] = {};
    for (int k0 = 0; k0 < EMBED; k0 += 32) {
        __syncthreads();
        // stage A 128x32 (2 rounds) + B 64x32 (1 round)
#pragma unroll
        for (int j = 0; j < 2; ++j) {
            int g = j * 4 + w;       // 16-row group 0..7
            GLD16(Ab + (size_t)(g * 16 + srow) * EMBED + k0 + scol, &As[g * 512]);
        }
        GLD16(Bb + (size_t)(w * 16 + srow) * EMBED + k0 + scol, &Bs[w * 512]);
        __syncthreads();             // compiler drains vmcnt before barrier

        bf16x8 af[2], bfr[4];
#pragma unroll
        for (int ta = 0; ta < 2; ++ta)
            af[ta] = *(const bf16x8*)&As[(w * 32 + ta * 16 + m16) * 32 + quad * 8];
#pragma unroll
        for (int tb = 0; tb < 4; ++tb)
            bfr[tb] = *(const bf16x8*)&Bs[(tb * 16 + m16) * 32 + quad * 8];
#pragma unroll
        for (int ta = 0; ta < 2; ++ta)
#pragma unroll
            for (int tb = 0; tb < 4; ++tb)
                acc[ta][tb] = __builtin_amdgcn_mfma_f32_16x16x32_bf16(
                    af[ta], bfr[tb], acc[ta][tb], 0, 0, 0);
    }

#pragma unroll
    for (int tb = 0; tb < 4; ++tb) {
        int col = n0 + tb * 16 + m16;
        float bias = bo[col];
#pragma unroll
        for (int ta = 0; ta < 2; ++ta)
#pragma unroll
            for (int r = 0; r < 4; ++r) {
                int row = m0 + w * 32 + ta * 16 + quad * 4 + r;
                out[(size_t)row * EMBED + col] = acc[ta][tb][r] + bias;
            }
    }
}

// ---------------------------------------------------------------------------
extern "C" void kernel_launch(void* const* d_in, const int* in_sizes, int n_in,
                              void* d_out, int out_size, void* d_ws, size_t ws_size,
                              hipStream_t stream) {
    const float* vals = (const float*)d_in[0];
    const float* keys = (const float*)d_in[1];
    const float* quer = (const float*)d_in[2];
    const float* Wv   = (const float*)d_in[3];
    const float* Wk   = (const float*)d_in[4];
    const float* Wq   = (const float*)d_in[5];
    const float* Wo   = (const float*)d_in[6];
    const float* bo   = (const float*)d_in[7];
    float* out = (float*)d_out;

    __hip_bfloat16* ws = (__hip_bfloat16*)d_ws;
    const size_t PE = (size_t)NB * HEADS * LSEQ * HD;   // 4,194,304
    __hip_bfloat16* Qp  = ws;
    __hip_bfloat16* Kp  = ws + PE;
    __hip_bfloat16* Vt  = ws + 2 * PE;
    __hip_bfloat16* AO  = ws + 3 * PE;
    __hip_bfloat16* Wob = ws + 4 * PE;

    proj_kernel<<<3 * NB * (LSEQ / 64) * (HEADS / 4), 256, 0, stream>>>(
        vals, keys, quer, Wv, Wk, Wq, Qp, Kp, Vt);
    wcvt_kernel<<<256, 256, 0, stream>>>(Wo, Wob);
    attn_kernel<<<2048, 256, 0, stream>>>(Qp, Kp, Vt, AO);
    outproj_kernel<<<512, 256, 0, stream>>>(AO, Wob, bo, out);
}

// Round 8
// 183.768 us; speedup vs baseline: 1.5395x; 1.5395x over previous
//
#include <hip/hip_runtime.h>
#include <hip/hip_bf16.h>

#define EMBED 1024
#define HEADS 16
#define HD 64
#define NB 2
#define LSEQ 2048

typedef __bf16 bf16x8 __attribute__((ext_vector_type(8)));
typedef float f32x4 __attribute__((ext_vector_type(4)));

static __device__ __forceinline__ __bf16 f2b(float x) {
    union { __hip_bfloat16 h; __bf16 b; } u;
    u.h = __float2bfloat16(x);
    return u.b;
}
static __device__ __forceinline__ bf16x8 cvt8(float4 a, float4 b) {
    bf16x8 r;
    r[0] = f2b(a.x); r[1] = f2b(a.y); r[2] = f2b(a.z); r[3] = f2b(a.w);
    r[4] = f2b(b.x); r[5] = f2b(b.y); r[6] = f2b(b.z); r[7] = f2b(b.w);
    return r;
}
static __device__ __forceinline__ unsigned short b2u(float x) {
    union { __hip_bfloat16 h; unsigned short u; } c;
    c.h = __float2bfloat16(x);
    return c.u;
}

// async global->LDS, 16B per lane
#define GLD16(g, l) __builtin_amdgcn_global_load_lds( \
    (const __attribute__((address_space(1))) void*)(g), \
    (__attribute__((address_space(3))) void*)(l), 16, 0, 0)

// ---------------------------------------------------------------------------
// FRAGMENT-ORDER layouts (per nh, all 131072 bf16):
//  QF: [T=q/16][kk][lane=quad*16+(q&15)][j]  elem = Q[q][kk*32+quad*8+j]
//  KF: [c=key/32][t2*2+kk][lane=quad*16+j2][j] elem = K[c*32+2*j2+t2][kk*32+quad*8+j]
//      (keys interleaved within chunk: tile t2 holds keys {2*j2+t2})
//  VF: [c][f=d/16][lane=quad*16+(d&15)][j]   elem = V[d][c*32+quad*8+j]
// Attention then loads every fragment as ONE lane-contiguous 1KB instruction.
// ---------------------------------------------------------------------------

// ---------------------------------------------------------------------------
// Kernel 1: QKV projection via MFMA, fp32 in, bf16 out in fragment order.
// Q scaled by log2(e)/32 (exp2 domain). Q/K: D = W·X^T (C rows = e, 4 regs
// d-contiguous -> 8B store); V: D = X·W^T (C rows = key, 4 regs key-contiguous
// -> 8B store). Layouts HW-verified: A[m=lane&15][k=quad*8+j];
// B[n=lane&15][k=quad*8+j]; C/D col=lane&15, row=quad*4+reg.
// ---------------------------------------------------------------------------
__global__ __launch_bounds__(256) void proj_kernel(
    const float* __restrict__ vals,
    const float* __restrict__ keys,
    const float* __restrict__ quer,
    const float* __restrict__ Wv,
    const float* __restrict__ Wk,
    const float* __restrict__ Wq,
    __hip_bfloat16* __restrict__ QF,
    __hip_bfloat16* __restrict__ KF,
    __hip_bfloat16* __restrict__ VF)
{
    int b      = blockIdx.x;
    int tensor = b % 3;
    int rem    = b / 3;                 // [n(1) | lt(5) | hg(2)]
    int n      = rem >> 7;
    int lt     = (rem >> 2) & 31;
    int hg     = rem & 3;
    int t = threadIdx.x, w = t >> 6, lane = t & 63;
    int m16 = lane & 15, quad = lane >> 4;
    int l0 = lt * 64 + w * 16;

    const float* X = (tensor == 0) ? quer : (tensor == 1 ? keys : vals);
    const float* W = (tensor == 0) ? Wq   : (tensor == 1 ? Wk   : Wv);
    float scale = (tensor == 0) ? (1.44269504088896340736f / 32.0f) : 1.0f;

    bf16x8 wf[4][2];
#pragma unroll
    for (int f = 0; f < 4; ++f)
#pragma unroll
        for (int kk = 0; kk < 2; ++kk) {
            const float* wp = W + (f * 16 + m16) * HD + kk * 32 + quad * 8;
            wf[f][kk] = cvt8(*(const float4*)wp, *(const float4*)(wp + 4));
        }

#pragma unroll
    for (int hh = 0; hh < 4; ++hh) {
        int h = hg * 4 + hh;
        const float* xb = X + ((size_t)n * LSEQ + l0 + m16) * EMBED + h * HD + quad * 8;
        bf16x8 xf[2];
#pragma unroll
        for (int kk = 0; kk < 2; ++kk)
            xf[kk] = cvt8(*(const float4*)(xb + kk * 32), *(const float4*)(xb + kk * 32 + 4));

        size_t nhb = (size_t)(n * HEADS + h) * 131072;
        if (tensor != 2) {
            // D = W·X^T: lane holds Y[e=f*16+quad*4+r][key/q = l0+m16]
            f32x4 acc[4] = {};
#pragma unroll
            for (int f = 0; f < 4; ++f) {
                acc[f] = __builtin_amdgcn_mfma_f32_16x16x32_bf16(wf[f][0], xf[0], acc[f], 0, 0, 0);
                acc[f] = __builtin_amdgcn_mfma_f32_16x16x32_bf16(wf[f][1], xf[1], acc[f], 0, 0, 0);
            }
            int key = l0 + m16;
#pragma unroll
            for (int f = 0; f < 4; ++f) {
                union { ushort4 u; unsigned short s[4]; } p;
#pragma unroll
                for (int r = 0; r < 4; ++r) p.s[r] = b2u(acc[f][r] * scale);
                int kk   = f >> 1;
                int qk2  = (f & 1) * 2 + (quad >> 1);   // d-quad in fragment
                int j4   = (quad & 1) * 4;              // d&7 base
                __hip_bfloat16* dst;
                if (tensor == 0) {
                    // QF: T*1024 + kk*512 + (qk2*16 + q&15)*8 + j4
                    dst = QF + nhb + (size_t)(l0 >> 4) * 1024 + kk * 512
                        + (qk2 * 16 + m16) * 8 + j4;
                } else {
                    // KF: c*2048 + ((key&1)*2+kk)*512 + (qk2*16 + (key&31)>>1)*8 + j4
                    dst = KF + nhb + (size_t)(key >> 5) * 2048
                        + ((key & 1) * 2 + kk) * 512
                        + (qk2 * 16 + ((key & 31) >> 1)) * 8 + j4;
                }
                *(ushort4*)dst = p.u;
            }
        } else {
            // D = X·W^T: lane holds V[key = l0+quad*4+r][d = f*16+m16]
            f32x4 acc[4] = {};
#pragma unroll
            for (int f = 0; f < 4; ++f) {
                acc[f] = __builtin_amdgcn_mfma_f32_16x16x32_bf16(xf[0], wf[f][0], acc[f], 0, 0, 0);
                acc[f] = __builtin_amdgcn_mfma_f32_16x16x32_bf16(xf[1], wf[f][1], acc[f], 0, 0, 0);
            }
            int keyq  = l0 + quad * 4;
            int c     = keyq >> 5;
            int quadv = (keyq & 31) >> 3;
            int j4    = (quad & 1) * 4;
#pragma unroll
            for (int f = 0; f < 4; ++f) {
                union { ushort4 u; unsigned short s[4]; } p;
#pragma unroll
                for (int r = 0; r < 4; ++r) p.s[r] = b2u(acc[f][r]);
                __hip_bfloat16* dst = VF + nhb + (size_t)c * 2048 + f * 512
                    + quadv * 128 + m16 * 8 + j4;
                *(ushort4*)dst = p.u;
            }
        }
    }
}

// ---------------------------------------------------------------------------
// Kernel 1b: Wo fp32 -> bf16.
// ---------------------------------------------------------------------------
__global__ __launch_bounds__(256) void wcvt_kernel(
    const float* __restrict__ Wo, __hip_bfloat16* __restrict__ Wob)
{
    int base = (blockIdx.x * 256 + threadIdx.x) * 16;
#pragma unroll
    for (int j = 0; j < 16; j += 4) {
        float4 w4 = *(const float4*)(Wo + base + j);
        __hip_bfloat16 o[4] = {
            __float2bfloat16(w4.x), __float2bfloat16(w4.y),
            __float2bfloat16(w4.z), __float2bfloat16(w4.w)};
        *(ushort4*)(Wob + base + j) = *(const ushort4*)o;
    }
}

// ---------------------------------------------------------------------------
// Kernel 2: flash attention v5 = round-5 structure + fragment-order loads.
// 1024 blocks x 4 waves: wave (qh=w&1, kh=w>>1) = 32 q x 1024 keys (32
// chunks of 32 keys). ALL global loads lane-contiguous 1KB. exp2-domain
// scores; P packed by v_perm truncation, one b32 LDS write/pair; P pipelined
// through double-buffered per-wave LDS (no in-loop barrier). 2-way split-K
// combined exactly via LDS. #pragma unroll 1 guards VGPR (round-7 lesson).
// ---------------------------------------------------------------------------
#define CHUNKS 32
__global__ __launch_bounds__(256) void attn_kernel(
    const __hip_bfloat16* __restrict__ QF,
    const __hip_bfloat16* __restrict__ KF,
    const __hip_bfloat16* __restrict__ VF,
    __hip_bfloat16* __restrict__ AO)
{
    __shared__ __align__(16) __hip_bfloat16 Pb[2][4][32][40];  // 20480 B

    int i  = blockIdx.x;              // 1024
    int x  = i & 7, r2 = i >> 3;      // XCD swizzle: 4 heads pinned per XCD
    int nh = x * 4 + (r2 >> 5);       // 0..31
    int qblk = r2 & 31;

    int t = threadIdx.x, w = t >> 6, lane = t & 63;
    int m16 = lane & 15, quad = lane >> 4;
    int qh = w & 1, kh = w >> 1;
    int q0 = qblk * 64 + qh * 32;
    size_t nhb = (size_t)nh * 131072;

    // Q fragments: lane-contiguous from QF
    const __hip_bfloat16* qb = QF + nhb + (size_t)(q0 >> 4) * 1024 + lane * 8;
    bf16x8 qf[2][2];
#pragma unroll
    for (int tq = 0; tq < 2; ++tq)
#pragma unroll
        for (int kk = 0; kk < 2; ++kk)
            qf[tq][kk] = *(const bf16x8*)(qb + tq * 1024 + kk * 512);

    const __hip_bfloat16* kp = KF + nhb + (size_t)(kh * 32) * 2048 + lane * 8;
    const __hip_bfloat16* vp = VF + nhb + (size_t)(kh * 32) * 2048 + lane * 8;

    f32x4 of[2][4] = {};
    float ls[2][4] = {};
    bf16x8 kf[2][2], vf[4], pf[2];

#pragma unroll 1
    for (int c = 0; c <= CHUNKS; ++c) {
        if (c < CHUNKS) {  // K(c): 4 contiguous 1KB loads
            const __hip_bfloat16* kc = kp + (size_t)c * 2048;
            kf[0][0] = *(const bf16x8*)(kc);
            kf[0][1] = *(const bf16x8*)(kc + 512);
            kf[1][0] = *(const bf16x8*)(kc + 1024);
            kf[1][1] = *(const bf16x8*)(kc + 1536);
        }
        if (c > 0) {       // read P(c-1), PV with V(c-1)
            pf[0] = *(const bf16x8*)&Pb[(c - 1) & 1][w][m16][quad * 8];
            pf[1] = *(const bf16x8*)&Pb[(c - 1) & 1][w][16 + m16][quad * 8];
#pragma unroll
            for (int tq = 0; tq < 2; ++tq)
#pragma unroll
                for (int f = 0; f < 4; ++f)
                    of[tq][f] = __builtin_amdgcn_mfma_f32_16x16x32_bf16(
                        pf[tq], vf[f], of[tq][f], 0, 0, 0);
        }
        if (c < CHUNKS) {
            const __hip_bfloat16* vc = vp + (size_t)c * 2048;
#pragma unroll
            for (int f = 0; f < 4; ++f)   // V(c): contiguous, used next iter
                vf[f] = *(const bf16x8*)(vc + f * 512);

            // S(c): tile t2 = keys {2j+t2} -> lane col m16 = keys 2m16+t2
            f32x4 s[2][2];
#pragma unroll
            for (int tq = 0; tq < 2; ++tq)
#pragma unroll
                for (int t2 = 0; t2 < 2; ++t2) {
                    f32x4 z = {};
                    z = __builtin_amdgcn_mfma_f32_16x16x32_bf16(qf[tq][0], kf[t2][0], z, 0, 0, 0);
                    z = __builtin_amdgcn_mfma_f32_16x16x32_bf16(qf[tq][1], kf[t2][1], z, 0, 0, 0);
                    s[tq][t2] = z;
                }
#pragma unroll
            for (int tq = 0; tq < 2; ++tq)
#pragma unroll
                for (int r = 0; r < 4; ++r) {
                    float e0 = __builtin_amdgcn_exp2f(s[tq][0][r]);  // key 2m16
                    float e1 = __builtin_amdgcn_exp2f(s[tq][1][r]);  // key 2m16+1
                    ls[tq][r] += e0 + e1;
                    unsigned u = __builtin_amdgcn_perm(
                        __float_as_uint(e1), __float_as_uint(e0), 0x07060302);
                    *(unsigned*)&Pb[c & 1][w][tq * 16 + quad * 4 + r][2 * m16] = u;
                }
        }
    }

    // reduce ls over the 16 key-lanes
#pragma unroll
    for (int tq = 0; tq < 2; ++tq)
#pragma unroll
        for (int r = 0; r < 4; ++r) {
            float v = ls[tq][r];
            v += __shfl_xor(v, 1);
            v += __shfl_xor(v, 2);
            v += __shfl_xor(v, 4);
            v += __shfl_xor(v, 8);
            ls[tq][r] = v;
        }

    // ---- 2-way split-K combine via LDS (reuse Pb) ----
    __syncthreads();
    float* Cb = (float*)&Pb[0][0][0][0];
    if (kh == 1) {
        int base = qh * 2560;
#pragma unroll
        for (int tq = 0; tq < 2; ++tq)
#pragma unroll
            for (int f = 0; f < 4; ++f)
                *(f32x4*)&Cb[base + (tq * 4 + f) * 256 + lane * 4] = of[tq][f];
#pragma unroll
        for (int tq = 0; tq < 2; ++tq)
#pragma unroll
            for (int r = 0; r < 4; ++r)
                Cb[base + 2048 + (tq * 4 + r) * 64 + lane] = ls[tq][r];
    }
    __syncthreads();
    if (kh == 0) {
        int base = qh * 2560;
#pragma unroll
        for (int tq = 0; tq < 2; ++tq)
#pragma unroll
            for (int f = 0; f < 4; ++f)
                of[tq][f] += *(const f32x4*)&Cb[base + (tq * 4 + f) * 256 + lane * 4];
        int n = nh >> 4, h = nh & 15;
#pragma unroll
        for (int tq = 0; tq < 2; ++tq)
#pragma unroll
            for (int r = 0; r < 4; ++r) {
                float lt2 = ls[tq][r] + Cb[base + 2048 + (tq * 4 + r) * 64 + lane];
                float rinv = 1.0f / lt2;
                int qrow = q0 + tq * 16 + quad * 4 + r;
#pragma unroll
                for (int f = 0; f < 4; ++f) {
                    int col = h * HD + f * 16 + m16;
                    AO[((size_t)n * LSEQ + qrow) * EMBED + col] =
                        __float2bfloat16(of[tq][f][r] * rinv);
                }
            }
    }
}

// ---------------------------------------------------------------------------
// Kernel 3: out = AO @ Wob^T + bo (fp32 out), LDS-staged GEMM, tile 128x64,
// BK=32, global_load_lds width-16 staging. 512 blocks of 256.
// ---------------------------------------------------------------------------
__global__ __launch_bounds__(256) void outproj_kernel(
    const __hip_bfloat16* __restrict__ AO,
    const __hip_bfloat16* __restrict__ Wob,
    const float* __restrict__ bo,
    float* __restrict__ out)
{
    __shared__ __align__(16) __hip_bfloat16 As[128 * 32];  // 8 KB
    __shared__ __align__(16) __hip_bfloat16 Bs[64 * 32];   // 4 KB

    int b  = blockIdx.x;
    int mt = b >> 4, nt = b & 15;
    int m0 = mt * 128, n0 = nt * 64;
    int t = threadIdx.x, w = t >> 6, lane = t & 63;
    int m16 = lane & 15, quad = lane >> 4;

    int srow = lane >> 2;
    int scol = (lane & 3) * 8;

    const __hip_bfloat16* Ab = AO  + (size_t)m0 * EMBED;
    const __hip_bfloat16* Bb = Wob + (size_t)n0 * EMBED;

    f32x4 acc[2][4] = {};
    for (int k0 = 0; k0 < EMBED; k0 += 32) {
        __syncthreads();
#pragma unroll
        for (int j = 0; j < 2; ++j) {
            int g = j * 4 + w;
            GLD16(Ab + (size_t)(g * 16 + srow) * EMBED + k0 + scol, &As[g * 512]);
        }
        GLD16(Bb + (size_t)(w * 16 + srow) * EMBED + k0 + scol, &Bs[w * 512]);
        __syncthreads();

        bf16x8 af[2], bfr[4];
#pragma unroll
        for (int ta = 0; ta < 2; ++ta)
            af[ta] = *(const bf16x8*)&As[(w * 32 + ta * 16 + m16) * 32 + quad * 8];
#pragma unroll
        for (int tb = 0; tb < 4; ++tb)
            bfr[tb] = *(const bf16x8*)&Bs[(tb * 16 + m16) * 32 + quad * 8];
#pragma unroll
        for (int ta = 0; ta < 2; ++ta)
#pragma unroll
            for (int tb = 0; tb < 4; ++tb)
                acc[ta][tb] = __builtin_amdgcn_mfma_f32_16x16x32_bf16(
                    af[ta], bfr[tb], acc[ta][tb], 0, 0, 0);
    }

#pragma unroll
    for (int tb = 0; tb < 4; ++tb) {
        int col = n0 + tb * 16 + m16;
        float bias = bo[col];
#pragma unroll
        for (int ta = 0; ta < 2; ++ta)
#pragma unroll
            for (int r = 0; r < 4; ++r) {
                int row = m0 + w * 32 + ta * 16 + quad * 4 + r;
                out[(size_t)row * EMBED + col] = acc[ta][tb][r] + bias;
            }
    }
}

// ---------------------------------------------------------------------------
extern "C" void kernel_launch(void* const* d_in, const int* in_sizes, int n_in,
                              void* d_out, int out_size, void* d_ws, size_t ws_size,
                              hipStream_t stream) {
    const float* vals = (const float*)d_in[0];
    const float* keys = (const float*)d_in[1];
    const float* quer = (const float*)d_in[2];
    const float* Wv   = (const float*)d_in[3];
    const float* Wk   = (const float*)d_in[4];
    const float* Wq   = (const float*)d_in[5];
    const float* Wo   = (const float*)d_in[6];
    const float* bo   = (const float*)d_in[7];
    float* out = (float*)d_out;

    __hip_bfloat16* ws = (__hip_bfloat16*)d_ws;
    const size_t PE = (size_t)NB * HEADS * LSEQ * HD;   // 4,194,304
    __hip_bfloat16* QF  = ws;
    __hip_bfloat16* KF  = ws + PE;
    __hip_bfloat16* VF  = ws + 2 * PE;
    __hip_bfloat16* AO  = ws + 3 * PE;
    __hip_bfloat16* Wob = ws + 4 * PE;

    proj_kernel<<<3 * NB * (LSEQ / 64) * (HEADS / 4), 256, 0, stream>>>(
        vals, keys, quer, Wv, Wk, Wq, QF, KF, VF);
    wcvt_kernel<<<256, 256, 0, stream>>>(Wo, Wob);
    attn_kernel<<<1024, 256, 0, stream>>>(QF, KF, VF, AO);
    outproj_kernel<<<512, 256, 0, stream>>>(AO, Wob, bo, out);
}